// Round 1
// baseline (30.633 us; speedup 1.0000x reference)
//
#include <hip/hip_runtime.h>

#define BATCH 4096
#define CLEN  8192
#define COEF  0.1f
#define NTHREADS 256

// Kernel 1: one block per row b.
// partial[b] = inv_norm(t_b) * sum_i |i - t_b| * exp(x[b,i])
__global__ __launch_bounds__(NTHREADS) void dfal_row_kernel(
    const float* __restrict__ in,
    const int*   __restrict__ target,
    float*       __restrict__ row_out)
{
    const int b   = blockIdx.x;
    const int tid = threadIdx.x;

    const long long t = (long long)target[b];

    // Exact sum of squared distances: sum_{i=0}^{C-1} (i-t)^2
    //   = t(t+1)(2t+1)/6 + m(m+1)(2m+1)/6,  m = C-1-t
    const long long m  = (long long)(CLEN - 1) - t;
    const long long ss = t * (t + 1) * (2 * t + 1) / 6
                       + m * (m + 1) * (2 * m + 1) / 6;
    const float inv_norm = (t == 0) ? 0.0f : (float)(1.0 / sqrt((double)ss));

    const float4* __restrict__ in4 = (const float4*)(in + (size_t)b * CLEN);
    const float tf = (float)t;

    float acc = 0.0f;
#pragma unroll
    for (int j = tid; j < CLEN / 4; j += NTHREADS) {
        const float4 x = in4[j];
        const float i0 = (float)(4 * j);
        acc = fmaf(fabsf(i0        - tf), __expf(x.x), acc);
        acc = fmaf(fabsf(i0 + 1.0f - tf), __expf(x.y), acc);
        acc = fmaf(fabsf(i0 + 2.0f - tf), __expf(x.z), acc);
        acc = fmaf(fabsf(i0 + 3.0f - tf), __expf(x.w), acc);
    }

    // Wave (64-lane) reduction
#pragma unroll
    for (int off = 32; off > 0; off >>= 1)
        acc += __shfl_down(acc, off, 64);

    __shared__ float wsum[NTHREADS / 64];
    const int lane = tid & 63;
    const int wid  = tid >> 6;
    if (lane == 0) wsum[wid] = acc;
    __syncthreads();

    if (tid == 0) {
        float s = 0.0f;
#pragma unroll
        for (int w = 0; w < NTHREADS / 64; ++w) s += wsum[w];
        row_out[b] = s * inv_norm;
    }
}

// Kernel 2: deterministic reduce of BATCH partials -> scalar * COEF
__global__ __launch_bounds__(NTHREADS) void dfal_reduce_kernel(
    const float* __restrict__ row_in,
    float*       __restrict__ out)
{
    const int tid = threadIdx.x;
    float acc = 0.0f;
#pragma unroll
    for (int i = tid; i < BATCH; i += NTHREADS)
        acc += row_in[i];

#pragma unroll
    for (int off = 32; off > 0; off >>= 1)
        acc += __shfl_down(acc, off, 64);

    __shared__ float wsum[NTHREADS / 64];
    const int lane = tid & 63;
    const int wid  = tid >> 6;
    if (lane == 0) wsum[wid] = acc;
    __syncthreads();

    if (tid == 0) {
        float s = 0.0f;
#pragma unroll
        for (int w = 0; w < NTHREADS / 64; ++w) s += wsum[w];
        out[0] = s * COEF;
    }
}

extern "C" void kernel_launch(void* const* d_in, const int* in_sizes, int n_in,
                              void* d_out, int out_size, void* d_ws, size_t ws_size,
                              hipStream_t stream) {
    const float* input  = (const float*)d_in[0];
    const int*   target = (const int*)d_in[1];
    float* out      = (float*)d_out;
    float* row_part = (float*)d_ws;  // BATCH floats of scratch

    dfal_row_kernel<<<BATCH, NTHREADS, 0, stream>>>(input, target, row_part);
    dfal_reduce_kernel<<<1, NTHREADS, 0, stream>>>(row_part, out);
}